// Round 6
// baseline (107.066 us; speedup 1.0000x reference)
//
#include <hip/hip_runtime.h>
#include <math.h>

#define BB 256
#define NN 1024
#define DD 128
#define NCHUNK 4
#define ROWS (NN / NCHUNK)   // 256

// workspace layout (in floats)
#define PA_OFF   0
#define PC_OFF   (NCHUNK*BB*DD)            // 131072
#define PCNT_OFF (2*NCHUNK*BB*DD)          // 262144
#define U_OFF    (PCNT_OFF + NCHUNK*BB)    // 263168
#define V_OFF    (U_OFF + BB*DD)           // 295936
// total = 328704 floats = 1.32 MB

// ---------------------------------------------------------------------------
// Kernel 1: masked streaming reductions over N.
//   P_A[chunk][b][k] = sum_{n in chunk} (mi-mj) * d[b,n,k]
//   P_C[chunk][b][k] = sum_{n in chunk} (mi*si - mj*sj)[b,n,k]
//   P_cnt[chunk][b]  = sum_{n in chunk} (mi-mj)
// grid = (NCHUNK, BB), block = 256 (32 lanes x 8 row-groups), float4 loads.
// ---------------------------------------------------------------------------
__global__ __launch_bounds__(256) void k1_reduce(
    const float* __restrict__ d, const float* __restrict__ si,
    const float* __restrict__ sj, const void* __restrict__ miv,
    const void* __restrict__ mjv, float* __restrict__ ws)
{
    const int chunk = blockIdx.x;
    const int b     = blockIdx.y;
    const int t     = threadIdx.x;
    const int lane  = t & 31;   // float4 column group: cols lane*4 .. +3
    const int rg    = t >> 5;   // row group 0..7

    // ---- mask dtype auto-detect (bool bytes vs int32) ----
    __shared__ int s_mode;
    if (t == 0) s_mode = 0;
    __syncthreads();
    {
        const unsigned int* a = (const unsigned int*)miv;
        const unsigned int* c = (const unsigned int*)mjv;
        if ((a[t] | c[t]) > 1u) s_mode = 1;  // bytes of 0/1 packed in a word
    }
    __syncthreads();
    const bool bytes_mode = (s_mode != 0);

    const unsigned char* mi8 = (const unsigned char*)miv;
    const unsigned char* mj8 = (const unsigned char*)mjv;
    const int*           mii = (const int*)miv;
    const int*           mji = (const int*)mjv;

    const int    n0      = chunk * ROWS;
    const size_t rowbase = (size_t)b * NN;

    float aA[4] = {0.f, 0.f, 0.f, 0.f};
    float aC[4] = {0.f, 0.f, 0.f, 0.f};
    float cnt   = 0.f;

    for (int it = 0; it < ROWS / 8; ++it) {
        const int    n = n0 + it * 8 + rg;
        const size_t m = rowbase + (size_t)n;
        const float fi = bytes_mode ? (float)mi8[m] : (float)mii[m];
        const float fj = bytes_mode ? (float)mj8[m] : (float)mji[m];
        const float wd = fi - fj;
        const size_t off = m * DD + (size_t)lane * 4;
        const float4 d4 = *(const float4*)(d  + off);
        const float4 x4 = *(const float4*)(si + off);
        const float4 y4 = *(const float4*)(sj + off);
        aA[0] += wd * d4.x; aA[1] += wd * d4.y;
        aA[2] += wd * d4.z; aA[3] += wd * d4.w;
        aC[0] += fi * x4.x - fj * y4.x;
        aC[1] += fi * x4.y - fj * y4.y;
        aC[2] += fi * x4.z - fj * y4.z;
        aC[3] += fi * x4.w - fj * y4.w;
        cnt += wd;   // identical across the 32 lanes of a row-group
    }

    // ---- reduce the 8 row-groups (t strides of 32) ----
    __shared__ float red[256][9];
    #pragma unroll
    for (int i = 0; i < 4; ++i) { red[t][i] = aA[i]; red[t][4 + i] = aC[i]; }
    red[t][8] = cnt;
    __syncthreads();
    if (t < 128) {
        #pragma unroll
        for (int i = 0; i < 9; ++i) red[t][i] += red[t + 128][i];
    }
    __syncthreads();
    if (t < 64) {
        #pragma unroll
        for (int i = 0; i < 9; ++i) red[t][i] += red[t + 64][i];
    }
    __syncthreads();
    if (t < 32) {
        #pragma unroll
        for (int i = 0; i < 9; ++i) red[t][i] += red[t + 32][i];
        float* PA = ws + PA_OFF + ((size_t)chunk * BB + b) * DD;
        float* PC = ws + PC_OFF + ((size_t)chunk * BB + b) * DD;
        #pragma unroll
        for (int i = 0; i < 4; ++i) {
            PA[t * 4 + i] = red[t][i];
            PC[t * 4 + i] = red[t][4 + i];
        }
        if (t == 0) ws[PCNT_OFF + chunk * BB + b] = red[0][8];
        // cnt was reduced across row-groups only (lanes hold identical
        // copies), so red[0][8] is exactly sum_n (mi-mj) for this chunk.
    }
}

// ---------------------------------------------------------------------------
// Kernel 2: M = relu(dm @ W1 + b1) fused with the w2 contraction:
//   u[b][p] = sum_q relu(dm[b]·W1[:,p*128+q] + b1[p*128+q]) * w2a[q]
//   v[b][p] = same with w2b
// grid = (128 p-tiles, 2 b-groups), block = 256 = 16 tx (q) x 16 ty (b).
// Each thread: 4 b x 8 q register tile over K=128.
// ---------------------------------------------------------------------------
__global__ __launch_bounds__(256) void k2_gemm(
    const float* __restrict__ d, const float* __restrict__ W1,
    const float* __restrict__ b1, const float* __restrict__ W2,
    float* __restrict__ ws)
{
    const int p  = blockIdx.x;      // output row of M (0..127)
    const int bg = blockIdx.y;      // batch group (0..1), 128 b each
    const int t  = threadIdx.x;
    const int tx = t & 15;          // q group: q0 = tx*8
    const int ty = t >> 4;          // b group: bb0 = ty*4

    __shared__ float w1s[128][128];  // [k][q]  64 KB
    __shared__ float dms[64][132];   // [bb][k] padded, ~34 KB
    __shared__ float b1s[128];
    __shared__ float w2as[128];
    __shared__ float w2bs[128];

    // stage W1 tile (coalesced: consecutive t -> consecutive q)
    for (int idx = t; idx < 128 * 128; idx += 256) {
        const int k = idx >> 7, q = idx & 127;
        w1s[k][q] = W1[(size_t)k * 16384 + p * 128 + q];
    }
    if (t < 128) {
        b1s[t]  = b1[p * 128 + t];
        w2as[t] = W2[t];
        w2bs[t] = W2[128 + t];
    }

    const int q0  = tx * 8;
    const int bb0 = ty * 4;

    for (int sc = 0; sc < 2; ++sc) {   // two sub-chunks of 64 batches
        const int b0 = bg * 128 + sc * 64;
        __syncthreads();   // protect dms reuse; also fences w1s staging (sc=0)
        for (int idx = t; idx < 64 * 128; idx += 256) {
            const int bb = idx >> 7, k = idx & 127;
            dms[bb][k] = d[(size_t)(b0 + bb) * NN * DD + k];  // d[b][0][k]
        }
        __syncthreads();

        float acc[4][8];
        #pragma unroll
        for (int i = 0; i < 4; ++i) {
            #pragma unroll
            for (int j = 0; j < 8; ++j) acc[i][j] = 0.f;
        }

        #pragma unroll 4
        for (int k = 0; k < 128; ++k) {
            float a0 = dms[bb0 + 0][k];
            float a1 = dms[bb0 + 1][k];
            float a2 = dms[bb0 + 2][k];
            float a3 = dms[bb0 + 3][k];
            const float4 wlo = *(const float4*)&w1s[k][q0];
            const float4 whi = *(const float4*)&w1s[k][q0 + 4];
            const float wq[8] = {wlo.x, wlo.y, wlo.z, wlo.w,
                                 whi.x, whi.y, whi.z, whi.w};
            #pragma unroll
            for (int j = 0; j < 8; ++j) {
                acc[0][j] = fmaf(a0, wq[j], acc[0][j]);
                acc[1][j] = fmaf(a1, wq[j], acc[1][j]);
                acc[2][j] = fmaf(a2, wq[j], acc[2][j]);
                acc[3][j] = fmaf(a3, wq[j], acc[3][j]);
            }
        }

        // relu + contract over this thread's 8 q's
        float uacc[4] = {0.f, 0.f, 0.f, 0.f};
        float vacc[4] = {0.f, 0.f, 0.f, 0.f};
        #pragma unroll
        for (int j = 0; j < 8; ++j) {
            const float bias = b1s[q0 + j];
            const float wa = w2as[q0 + j];
            const float wb = w2bs[q0 + j];
            #pragma unroll
            for (int i = 0; i < 4; ++i) {
                float g = fmaxf(acc[i][j] + bias, 0.f);
                uacc[i] += g * wa;
                vacc[i] += g * wb;
            }
        }

        // reduce over the 16 tx threads (lane groups of 16 within the wave)
        #pragma unroll
        for (int off = 8; off > 0; off >>= 1) {
            #pragma unroll
            for (int i = 0; i < 4; ++i) {
                uacc[i] += __shfl_down(uacc[i], off, 16);
                vacc[i] += __shfl_down(vacc[i], off, 16);
            }
        }
        if (tx == 0) {
            const int bbase = b0 + bb0;
            #pragma unroll
            for (int i = 0; i < 4; ++i) {
                ws[U_OFF + (size_t)(bbase + i) * DD + p] = uacc[i];
                ws[V_OFF + (size_t)(bbase + i) * DD + p] = vacc[i];
            }
        }
    }
}

// ---------------------------------------------------------------------------
// Kernel 3: per-batch score assembly + sigmoid.
//   out[b] = sigmoid( Adiff·u + Cdiff·v + b2*cntdiff )
// grid = 256, block = 64 (one wave per batch).
// ---------------------------------------------------------------------------
__global__ __launch_bounds__(64) void k3_final(
    const float* __restrict__ ws, const float* __restrict__ b2p,
    float* __restrict__ out)
{
    const int b = blockIdx.x;
    const int l = threadIdx.x;

    float s = 0.f;
    #pragma unroll
    for (int rep = 0; rep < 2; ++rep) {
        const int k = l + rep * 64;
        float A = 0.f, C = 0.f;
        #pragma unroll
        for (int c = 0; c < NCHUNK; ++c) {
            A += ws[PA_OFF + ((size_t)c * BB + b) * DD + k];
            C += ws[PC_OFF + ((size_t)c * BB + b) * DD + k];
        }
        s += A * ws[U_OFF + (size_t)b * DD + k]
           + C * ws[V_OFF + (size_t)b * DD + k];
    }
    #pragma unroll
    for (int off = 32; off > 0; off >>= 1) s += __shfl_down(s, off, 64);

    if (l == 0) {
        float cnt = 0.f;
        #pragma unroll
        for (int c = 0; c < NCHUNK; ++c) cnt += ws[PCNT_OFF + c * BB + b];
        const float score = s + b2p[0] * cnt;   // SCALING_FACTOR == 1.0
        out[b] = 1.f / (1.f + expf(-score));
    }
}

extern "C" void kernel_launch(void* const* d_in, const int* in_sizes, int n_in,
                              void* d_out, int out_size, void* d_ws, size_t ws_size,
                              hipStream_t stream)
{
    const float* d   = (const float*)d_in[0];
    const float* si  = (const float*)d_in[1];
    const float* sj  = (const float*)d_in[2];
    const void*  mi  = d_in[3];
    const void*  mj  = d_in[4];
    const float* W1  = (const float*)d_in[5];
    const float* b1  = (const float*)d_in[6];
    const float* W2  = (const float*)d_in[7];
    const float* b2  = (const float*)d_in[8];
    float* ws  = (float*)d_ws;
    float* out = (float*)d_out;

    dim3 g1(NCHUNK, BB);
    k1_reduce<<<g1, 256, 0, stream>>>(d, si, sj, mi, mj, ws);
    dim3 g2(128, 2);
    k2_gemm<<<g2, 256, 0, stream>>>(d, W1, b1, W2, ws);
    k3_final<<<BB, 64, 0, stream>>>(ws, b2, out);
}